// Round 14
// baseline (114.510 us; speedup 1.0000x reference)
//
#include <hip/hip_runtime.h>
#include <hip/hip_bf16.h>

#define HEADS 4
#define DHEAD 64
#define CC 128
#define NPOS 2560
#define NB 2
#define NSPLIT 4
#define NT_SPLIT ((NPOS / 64) / NSPLIT)   // 10

// workspace (shorts): [wb(98304)|wob(32768) in old xn slot] | q | k | v | o_ws | po[NSPLIT] | ml
#define XN_ELE  ((size_t)NB * NPOS * CC)             // 655360
#define QKV_ELE ((size_t)NB * HEADS * NPOS * DHEAD)  // 1310720
#define WS_BASE_BYTES  ((XN_ELE + 4 * QKV_ELE) * 2)                       // 11.25 MiB
#define WS_SPLIT_BYTES ((XN_ELE + (4 + NSPLIT) * QKV_ELE) * 2 \
                        + (size_t)NSPLIT * NB * HEADS * NPOS * 8)         // ~21.9 MiB

typedef __attribute__((ext_vector_type(8))) short short8;
typedef __attribute__((ext_vector_type(4))) short short4_t;
typedef __attribute__((ext_vector_type(4))) float f32x4;

// XOR-swizzled LDS index: 64-short (128B) rows, 16B-granule swizzle (T2).
#define SIDX(row, col) (((row) << 6) + ((col) ^ (((row) & 7) << 3)))

static __device__ __forceinline__ float b2f(short u) {
    union { unsigned int i; float f; } v;
    v.i = ((unsigned int)(unsigned short)u) << 16;
    return v.f;
}
static __device__ __forceinline__ short f2b(float f) {
    __hip_bfloat16 h = __float2bfloat16(f);
    union { __hip_bfloat16 h; unsigned short u; } v; v.h = h;
    return (short)v.u;
}

// -------- Kernel 0: one-shot weight conversion f32 -> bf16 (w_qkv | w_out) --------
__global__ __launch_bounds__(256) void wcvt_kernel(
    const float* __restrict__ wq, const float* __restrict__ wo, short* __restrict__ wb) {
    int gid = blockIdx.x * 256 + threadIdx.x;   // 0..16383
    int e0 = gid * 8;
    const float* src = (e0 < 98304) ? (wq + e0) : (wo + (e0 - 98304));
    f32x4 a = *(const f32x4*)src;
    f32x4 c = *(const f32x4*)(src + 4);
    short8 o = { f2b(a[0]), f2b(a[1]), f2b(a[2]), f2b(a[3]),
                 f2b(c[0]), f2b(c[1]), f2b(c[2]), f2b(c[3]) };
    *(short8*)&wb[e0] = o;
}

// -------- Kernel 1: fused LayerNorm + QKV projection --------
// Phase 1: LN stats (each thread holds 32 consecutive c of one pos, coalesced loads).
// Phase 2: normalize in registers -> Xs (bf16). W staged from pre-converted bf16.
// Phase 3: MFMA + scatter epilogue (identical to proven qkv_kernel).
__global__ __launch_bounds__(256) void lnqkv_kernel(
    const float* __restrict__ x, const float* __restrict__ g,
    const float* __restrict__ bb, const short* __restrict__ wb,
    short* __restrict__ q_ws, short* __restrict__ k_ws, short* __restrict__ v_ws) {
    int pt = blockIdx.x, ot = blockIdx.y, b = blockIdx.z;
    int p0 = pt * 64, o0 = ot * 64;
    __shared__ short Ws[64][136];
    __shared__ short Xs[64][136];
    __shared__ float redsum[4][64], redsq[4][64], meanS[64], invS[64];
    int t = threadIdx.x, wv = t >> 6, l = t & 63;
    int p = t & 63, cpart = t >> 6;

    float xv[32];
    float s = 0.f, sq = 0.f;
    #pragma unroll
    for (int k = 0; k < 32; k++) {
        int c = cpart * 32 + k;
        float v = x[((b * CC + c) * NPOS) + p0 + p];
        xv[k] = v; s += v; sq += v * v;
    }
    redsum[cpart][p] = s; redsq[cpart][p] = sq;
    // stage W (bf16, 1024 short8 / 256 threads = 4 each) while reduce lands
    for (int i = 0; i < 4; i++) {
        int gidx = i * 256 + t;
        int r = gidx >> 4, ch = gidx & 15;
        *(short8*)&Ws[r][ch * 8] = *(const short8*)&wb[(size_t)(o0 + r) * CC + ch * 8];
    }
    __syncthreads();
    if (t < 64) {
        float S = redsum[0][t] + redsum[1][t] + redsum[2][t] + redsum[3][t];
        float Q = redsq[0][t] + redsq[1][t] + redsq[2][t] + redsq[3][t];
        float mean = S * (1.f / CC);
        float var = fmaxf(Q * (1.f / CC) - mean * mean, 0.f);
        meanS[t] = mean;
        invS[t] = 1.f / (sqrtf(var) + 1e-5f);
    }
    __syncthreads();
    float mean = meanS[p], inv = invS[p];
    #pragma unroll
    for (int u = 0; u < 4; u++) {
        short8 xo;
        #pragma unroll
        for (int j = 0; j < 8; j++) {
            int c = cpart * 32 + u * 8 + j;
            xo[j] = f2b((xv[u * 8 + j] - mean) * inv * g[c] + bb[c]);   // g,bb wave-uniform
        }
        *(short8*)&Xs[p][cpart * 32 + u * 8] = xo;
    }
    __syncthreads();

    f32x4 acc[4] = {{0,0,0,0},{0,0,0,0},{0,0,0,0},{0,0,0,0}};
    int lr = l & 15, lg = l >> 4;
    for (int kk = 0; kk < 4; kk++) {
        short8 a = *(short8*)&Ws[wv * 16 + lr][kk * 32 + lg * 8];
        for (int fb = 0; fb < 4; fb++) {
            short8 bf = *(short8*)&Xs[fb * 16 + lr][kk * 32 + lg * 8];
            acc[fb] = __builtin_amdgcn_mfma_f32_16x16x32_bf16(a, bf, acc[fb], 0, 0, 0);
        }
    }
    int orow0 = o0 + wv * 16 + lg * 4;
    int sec = orow0 >> 8;
    int oi = orow0 & 255, h = oi >> 6, d0 = oi & 63;
    size_t bh = (size_t)(b * HEADS + h);
    for (int fb = 0; fb < 4; fb++) {
        int pos = p0 + fb * 16 + lr;
        if (sec == 0) {
            short4_t qv = { f2b(acc[fb][0] * 0.125f), f2b(acc[fb][1] * 0.125f),
                            f2b(acc[fb][2] * 0.125f), f2b(acc[fb][3] * 0.125f) };
            *(short4_t*)&q_ws[(bh * NPOS + pos) * DHEAD + d0] = qv;
        } else if (sec == 1) {
            short4_t kv = { f2b(acc[fb][0]), f2b(acc[fb][1]), f2b(acc[fb][2]), f2b(acc[fb][3]) };
            *(short4_t*)&k_ws[(bh * NPOS + pos) * DHEAD + d0] = kv;
        } else {
            for (int r = 0; r < 4; r++)
                v_ws[(bh * DHEAD + d0 + r) * NPOS + pos] = f2b(acc[fb][r]);
        }
    }
}

// ======== flash-attention core: single-buffered K/V, async-stage split (T14), ========
// ======== defer-max (T13, THR=8). LDS = 24 KB -> 6 blocks/CU.                 ========
template <int NT>
static __device__ __forceinline__ void attn_core(
    const short* __restrict__ kbp, const short* __restrict__ vbp,
    const short8* qreg, int kt0,
    short* Ks, short* Vs, short* PsT,
    int t, float& m_, float& l_, f32x4* acc) {
    int wv = t >> 6, l = t & 63;
    int lr = l & 15, lg = l >> 4;
    int sr0 = t >> 3, sr1 = sr0 + 32, sc = (t & 7) * 8;
    int prow = wv * 16 + lr;

    {   // prologue: stage first tile
        int koff = kt0 * 64;
        *(short8*)&Ks[SIDX(sr0, sc)] = *(const short8*)&kbp[(size_t)(koff + sr0) * DHEAD + sc];
        *(short8*)&Ks[SIDX(sr1, sc)] = *(const short8*)&kbp[(size_t)(koff + sr1) * DHEAD + sc];
        *(short8*)&Vs[SIDX(sr0, sc)] = *(const short8*)&vbp[(size_t)sr0 * NPOS + koff + sc];
        *(short8*)&Vs[SIDX(sr1, sc)] = *(const short8*)&vbp[(size_t)sr1 * NPOS + koff + sc];
    }
    __syncthreads();

    for (int it = 0; it < NT; it++) {
        bool pf = (it + 1 < NT);
        short8 kr0, kr1, vr0, vr1;
        if (pf) {   // issue next tile's loads early; latency hides under compute
            int koff = (kt0 + it + 1) * 64;
            kr0 = *(const short8*)&kbp[(size_t)(koff + sr0) * DHEAD + sc];
            kr1 = *(const short8*)&kbp[(size_t)(koff + sr1) * DHEAD + sc];
            vr0 = *(const short8*)&vbp[(size_t)sr0 * NPOS + koff + sc];
            vr1 = *(const short8*)&vbp[(size_t)sr1 * NPOS + koff + sc];
        }
        // QK^T (swapped): sf[fb][r] = S^T[k=fb*16+lg*4+r][q=prow]
        f32x4 sf[4] = {{0,0,0,0},{0,0,0,0},{0,0,0,0},{0,0,0,0}};
        #pragma unroll
        for (int kk = 0; kk < 2; kk++) {
            #pragma unroll
            for (int fb = 0; fb < 4; fb++) {
                short8 kb = *(short8*)&Ks[SIDX(fb * 16 + lr, kk * 32 + lg * 8)];
                sf[fb] = __builtin_amdgcn_mfma_f32_16x16x32_bf16(kb, qreg[kk], sf[fb], 0, 0, 0);
            }
        }
        // row max (in-lane + 2 shuffles)
        float m0 = fmaxf(fmaxf(sf[0][0], sf[0][1]), fmaxf(sf[0][2], sf[0][3]));
        float m1 = fmaxf(fmaxf(sf[1][0], sf[1][1]), fmaxf(sf[1][2], sf[1][3]));
        float m2 = fmaxf(fmaxf(sf[2][0], sf[2][1]), fmaxf(sf[2][2], sf[2][3]));
        float m3 = fmaxf(fmaxf(sf[3][0], sf[3][1]), fmaxf(sf[3][2], sf[3][3]));
        float mx = fmaxf(fmaxf(m0, m1), fmaxf(m2, m3));
        mx = fmaxf(mx, __shfl_xor(mx, 16, 64));
        mx = fmaxf(mx, __shfl_xor(mx, 32, 64));
        // defer-max (T13): only rescale when max grew by > 8 (P bounded by e^8)
        if (!__all(mx - m_ <= 8.0f)) {
            float nm = fmaxf(m_, mx);
            float alpha = __expf(m_ - nm);
            l_ *= alpha;
            #pragma unroll
            for (int db = 0; db < 4; db++) {
                acc[db][0] *= alpha; acc[db][1] *= alpha;
                acc[db][2] *= alpha; acc[db][3] *= alpha;
            }
            m_ = nm;
        }
        float ps[4][4];
        float rs = 0.f;
        #pragma unroll
        for (int fb = 0; fb < 4; fb++) {
            float s0 = __expf(sf[fb][0] - m_), s1 = __expf(sf[fb][1] - m_);
            float s2 = __expf(sf[fb][2] - m_), s3 = __expf(sf[fb][3] - m_);
            ps[fb][0] = s0; ps[fb][1] = s1; ps[fb][2] = s2; ps[fb][3] = s3;
            rs += (s0 + s1) + (s2 + s3);
        }
        rs += __shfl_xor(rs, 16, 64);
        rs += __shfl_xor(rs, 32, 64);
        l_ += rs;
        // P^T rows (wave-private)
        #pragma unroll
        for (int fb = 0; fb < 4; fb++) {
            short4_t pk = { f2b(ps[fb][0]), f2b(ps[fb][1]), f2b(ps[fb][2]), f2b(ps[fb][3]) };
            *(short4_t*)&PsT[SIDX(prow, fb * 16 + lg * 4)] = pk;
        }
        // PV
        #pragma unroll
        for (int kk = 0; kk < 2; kk++) {
            short8 pb = *(short8*)&PsT[SIDX(prow, kk * 32 + lg * 8)];
            #pragma unroll
            for (int db = 0; db < 4; db++) {
                short8 va = *(short8*)&Vs[SIDX(db * 16 + lr, kk * 32 + lg * 8)];
                acc[db] = __builtin_amdgcn_mfma_f32_16x16x32_bf16(va, pb, acc[db], 0, 0, 0);
            }
        }
        if (pf) {   // land prefetched tile into the (single) buffer
            __syncthreads();   // all waves done reading K/V
            *(short8*)&Ks[SIDX(sr0, sc)] = kr0;
            *(short8*)&Ks[SIDX(sr1, sc)] = kr1;
            *(short8*)&Vs[SIDX(sr0, sc)] = vr0;
            *(short8*)&Vs[SIDX(sr1, sc)] = vr1;
            __syncthreads();   // writes visible
        }
    }
}

// -------- Kernel 2a: full-KV attention (fallback) --------
__global__ __launch_bounds__(256) void attn_kernel(
    const short* __restrict__ q_ws, const short* __restrict__ k_ws,
    const short* __restrict__ v_ws, short* __restrict__ o_ws) {
    int qt = blockIdx.x, bh = blockIdx.y;
    int q0 = qt * 64;
    __shared__ short Ks[64 * 64];
    __shared__ short Vs[64 * 64];
    __shared__ short PsT[64 * 64];
    int t = threadIdx.x, wv = t >> 6, l = t & 63;
    int lr = l & 15, lg = l >> 4;
    const short* kbp = k_ws + (size_t)bh * NPOS * DHEAD;
    const short* vbp = v_ws + (size_t)bh * DHEAD * NPOS;
    short8 qreg[2];
    for (int kk = 0; kk < 2; kk++)
        qreg[kk] = *(const short8*)&q_ws[((size_t)bh * NPOS + q0 + wv * 16 + lr) * DHEAD + kk * 32 + lg * 8];
    float m_ = -1e9f, l_ = 0.f;
    f32x4 acc[4] = {{0,0,0,0},{0,0,0,0},{0,0,0,0},{0,0,0,0}};
    attn_core<NPOS / 64>(kbp, vbp, qreg, 0, Ks, Vs, PsT, t, m_, l_, acc);
    int h = bh & (HEADS - 1), b = bh >> 2;
    float inv = 1.f / l_;
    int pos = q0 + wv * 16 + lr;
    #pragma unroll
    for (int db = 0; db < 4; db++) {
        short4_t ov = { f2b(acc[db][0] * inv), f2b(acc[db][1] * inv),
                        f2b(acc[db][2] * inv), f2b(acc[db][3] * inv) };
        *(short4_t*)&o_ws[((size_t)(b * NPOS) + pos) * 256 + h * DHEAD + db * 16 + lg * 4] = ov;
    }
}

// -------- Kernel 2b: split-KV attention -> po (normalized partial O) + ml (m,l) --------
__global__ __launch_bounds__(256) void attn_split_kernel(
    const short* __restrict__ q_ws, const short* __restrict__ k_ws,
    const short* __restrict__ v_ws, short* __restrict__ po, float* __restrict__ ml) {
    int qt = blockIdx.x, bh = blockIdx.y, s = blockIdx.z;
    int q0 = qt * 64;
    __shared__ short Ks[64 * 64];
    __shared__ short Vs[64 * 64];
    __shared__ short PsT[64 * 64];
    int t = threadIdx.x, wv = t >> 6, l = t & 63;
    int lr = l & 15, lg = l >> 4;
    const short* kbp = k_ws + (size_t)bh * NPOS * DHEAD;
    const short* vbp = v_ws + (size_t)bh * DHEAD * NPOS;
    short8 qreg[2];
    for (int kk = 0; kk < 2; kk++)
        qreg[kk] = *(const short8*)&q_ws[((size_t)bh * NPOS + q0 + wv * 16 + lr) * DHEAD + kk * 32 + lg * 8];
    float m_ = -1e9f, l_ = 0.f;
    f32x4 acc[4] = {{0,0,0,0},{0,0,0,0},{0,0,0,0},{0,0,0,0}};
    attn_core<NT_SPLIT>(kbp, vbp, qreg, s * NT_SPLIT, Ks, Vs, PsT, t, m_, l_, acc);
    float inv = 1.f / l_;
    int pos = q0 + wv * 16 + lr;
    size_t sb = (size_t)(s * NB * HEADS + bh);
    #pragma unroll
    for (int db = 0; db < 4; db++) {
        short4_t ov = { f2b(acc[db][0] * inv), f2b(acc[db][1] * inv),
                        f2b(acc[db][2] * inv), f2b(acc[db][3] * inv) };
        *(short4_t*)&po[(sb * NPOS + pos) * DHEAD + db * 16 + lg * 4] = ov;
    }
    if (lg == 0) {
        ml[2 * (sb * NPOS + pos) + 0] = m_;
        ml[2 * (sb * NPOS + pos) + 1] = l_;
    }
}

// -------- Kernel 3: output projection (bf16 W); SPLIT=true fuses the split-combine --------
template <bool SPLIT>
__global__ __launch_bounds__(256) void proj_kernel(
    const short* __restrict__ wob, const float* __restrict__ b_out,
    const short* __restrict__ o_ws, const short* __restrict__ po,
    const float* __restrict__ ml, float* __restrict__ out) {
    int pt = blockIdx.x, ct = blockIdx.y, b = blockIdx.z;
    int p0 = pt * 64, c0 = ct * 64;
    __shared__ short Ws[64][264];
    __shared__ short Os[64][264];
    int t = threadIdx.x, wv = t >> 6, l = t & 63;
    int lr = l & 15, lg = l >> 4;
    for (int i = 0; i < 8; i++) {             // W: 64x256 bf16 (2048 short8)
        int gidx = i * 256 + t;
        int r = gidx >> 5, ch = gidx & 31;
        *(short8*)&Ws[r][ch * 8] = *(const short8*)&wob[(size_t)(c0 + r) * 256 + ch * 8];
    }
    for (int i = 0; i < 8; i++) {             // O: 64x256, combined inline when SPLIT
        int gidx = i * 256 + t;
        int r = gidx >> 5, ch = gidx & 31;
        if constexpr (SPLIT) {
            int pos = p0 + r;
            int h = ch >> 3, d0 = (ch & 7) * 8;
            int bh = b * HEADS + h;
            float ms[NSPLIT], ls[NSPLIT], m = -1e30f;
            #pragma unroll
            for (int s = 0; s < NSPLIT; s++) {
                size_t sb = (size_t)(s * NB * HEADS + bh);
                ms[s] = ml[2 * (sb * NPOS + pos) + 0];
                ls[s] = ml[2 * (sb * NPOS + pos) + 1];
                m = fmaxf(m, ms[s]);
            }
            float w4[NSPLIT], wsum = 0.f;
            #pragma unroll
            for (int s = 0; s < NSPLIT; s++) { w4[s] = ls[s] * __expf(ms[s] - m); wsum += w4[s]; }
            float o8[8] = {0,0,0,0,0,0,0,0};
            #pragma unroll
            for (int s = 0; s < NSPLIT; s++) {
                size_t sb = (size_t)(s * NB * HEADS + bh);
                short8 v = *(const short8*)&po[(sb * NPOS + pos) * DHEAD + d0];
                #pragma unroll
                for (int j = 0; j < 8; j++) o8[j] += w4[s] * b2f(v[j]);
            }
            float invw = 1.f / wsum;
            short8 ov;
            #pragma unroll
            for (int j = 0; j < 8; j++) ov[j] = f2b(o8[j] * invw);
            *(short8*)&Os[r][ch * 8] = ov;
        } else {
            *(short8*)&Os[r][ch * 8] = *(const short8*)&o_ws[((size_t)(b * NPOS) + p0 + r) * 256 + ch * 8];
        }
    }
    __syncthreads();
    f32x4 acc[4] = {{0,0,0,0},{0,0,0,0},{0,0,0,0},{0,0,0,0}};
    for (int kc = 0; kc < 8; kc++) {
        short8 a = *(short8*)&Ws[wv * 16 + lr][kc * 32 + lg * 8];
        #pragma unroll
        for (int fb = 0; fb < 4; fb++) {
            short8 ob = *(short8*)&Os[fb * 16 + lr][kc * 32 + lg * 8];
            acc[fb] = __builtin_amdgcn_mfma_f32_16x16x32_bf16(a, ob, acc[fb], 0, 0, 0);
        }
    }
    for (int r = 0; r < 4; r++) {
        int c = c0 + wv * 16 + lg * 4 + r;
        float bias = b_out[c];
        for (int fb = 0; fb < 4; fb++) {
            float vv = acc[fb][r] + bias;
            out[((size_t)(b * CC) + c) * NPOS + p0 + fb * 16 + lr] = vv;
        }
    }
}

extern "C" void kernel_launch(void* const* d_in, const int* in_sizes, int n_in,
                              void* d_out, int out_size, void* d_ws, size_t ws_size,
                              hipStream_t stream) {
    const float* x     = (const float*)d_in[0];
    const float* g     = (const float*)d_in[1];
    const float* b     = (const float*)d_in[2];
    const float* w_qkv = (const float*)d_in[3];
    const float* w_out = (const float*)d_in[4];
    const float* b_out = (const float*)d_in[5];
    float* out = (float*)d_out;   // FLOAT32 output (verified R8)

    const size_t out_bytes = (size_t)out_size * sizeof(float);

    {   // Tripwire A: input ordering/sizes signature
        const int exp_sizes[6] = {655360, 128, 128, 98304, 32768, 128};
        int bad = -1;
        if (n_in != 6) bad = 15;
        else for (int i = 0; i < 6; i++) if (in_sizes[i] != exp_sizes[i]) { bad = i; break; }
        if (bad >= 0) { hipMemsetAsync(d_out, 0x50 | bad, out_bytes, stream); return; }
    }
    if (ws_size < WS_BASE_BYTES) {   // Tripwire B: workspace size
        int mb = (int)(ws_size >> 20); if (mb > 15) mb = 15;
        hipMemsetAsync(d_out, 0x40 | mb, out_bytes, stream);
        return;
    }

    short* wb   = (short*)d_ws;                         // 98304 (bf16 w_qkv), in old xn slot
    short* wob  = wb + 98304;                           // 32768 (bf16 w_out)
    short* q_ws = (short*)d_ws + XN_ELE;
    short* k_ws = q_ws + QKV_ELE;
    short* v_ws = k_ws + QKV_ELE;
    short* o_ws = v_ws + QKV_ELE;
    short* po   = o_ws + QKV_ELE;                       // NSPLIT x QKV_ELE
    float* ml   = (float*)(po + NSPLIT * QKV_ELE);      // NSPLIT x NB*HEADS*NPOS x float2

    const bool use_split = (ws_size >= WS_SPLIT_BYTES);

    (void)hipGetLastError();
    wcvt_kernel<<<dim3(64), 256, 0, stream>>>(w_qkv, w_out, wb);
    lnqkv_kernel<<<dim3(NPOS / 64, 12, NB), 256, 0, stream>>>(x, g, b, wb, q_ws, k_ws, v_ws);
    if (use_split) {
        attn_split_kernel<<<dim3(NPOS / 64, NB * HEADS, NSPLIT), 256, 0, stream>>>(q_ws, k_ws, v_ws, po, ml);
        proj_kernel<true><<<dim3(NPOS / 64, 2, NB), 256, 0, stream>>>(wob, b_out, o_ws, po, ml, out);
    } else {
        attn_kernel<<<dim3(NPOS / 64, NB * HEADS), 256, 0, stream>>>(q_ws, k_ws, v_ws, o_ws);
        proj_kernel<false><<<dim3(NPOS / 64, 2, NB), 256, 0, stream>>>(wob, b_out, o_ws, po, ml, out);
    }
    if (hipGetLastError() != hipSuccess) {   // Tripwire C: launch failure flood
        hipMemsetAsync(d_out, 0xF0, out_bytes, stream);
    }
}